// Round 1
// baseline (8510.815 us; speedup 1.0000x reference)
//
#include <hip/hip_runtime.h>
#include <math.h>

#define DD 128
#define BM 64
#define KC 64
#define APAD 68   // LDS stride for transposed A tile: 16B-aligned rows, staggered banks

// ---------------------------------------------------------------------------
// Fused gather * edge-weight -> scatter-add (segment_sum) via atomics.
// One thread = one edge x 4 consecutive columns (float4 gather, 4 atomicAdd).
// ---------------------------------------------------------------------------
__global__ __launch_bounds__(256) void k_scatter(
    const float* __restrict__ h, const int* __restrict__ src,
    const int* __restrict__ dst, const float* __restrict__ ew,
    float* __restrict__ agg, int E)
{
    int tid = blockIdx.x * 256 + threadIdx.x;
    int e = tid >> 5;
    if (e >= E) return;
    int c = (tid & 31) << 2;
    int s = src[e];
    int d = dst[e];
    float w = ew[e];
    float4 v = *(const float4*)(h + s * DD + c);
    float* a = agg + d * DD + c;
    atomicAdd(a + 0, v.x * w);
    atomicAdd(a + 1, v.y * w);
    atomicAdd(a + 2, v.z * w);
    atomicAdd(a + 3, v.w * w);
}

// ---------------------------------------------------------------------------
// Fused: out = PReLU(LayerNorm(agg @ Wrel + h @ Wroot + bias))
// Treated as one GEMM with concatenated K=256: A=[agg|h], W=[Wrel;Wroot].
// Block: 256 threads, 64 rows. Thread tile: 8 rows x 4 cols.
// LDS: W chunk (64x128) + transposed A chunk (64x64, stride APAD). ~50 KB.
// Row n is owned by a 32-lane half-wave -> LN via __shfl_xor width 32.
// ---------------------------------------------------------------------------
__global__ __launch_bounds__(256) void k_layer(
    const float* __restrict__ agg, const float* __restrict__ hin,
    const float* __restrict__ Wrel, const float* __restrict__ Wroot,
    const float* __restrict__ bias, const float* __restrict__ lng,
    const float* __restrict__ lnb, const float* __restrict__ alpha_p,
    float* __restrict__ hout, int N)
{
    __shared__ float sW[KC * DD];       // 32 KiB
    __shared__ float sAT[KC * APAD];    // 17 KiB, sAT[k][r]

    const int t  = threadIdx.x;
    const int tx = t & 31;              // col group: cols tx*4 .. tx*4+3
    const int ty = t >> 5;              // row group: rows ty*8 .. ty*8+7
    const int n0 = blockIdx.x * BM;

    float acc[8][4];
    #pragma unroll
    for (int i = 0; i < 8; ++i)
        #pragma unroll
        for (int j = 0; j < 4; ++j) acc[i][j] = 0.f;

    #pragma unroll
    for (int ch = 0; ch < 4; ++ch) {
        const float* A = (ch < 2) ? agg  : hin;
        const float* W = (ch < 2) ? Wrel : Wroot;
        const int kbase = (ch & 1) * KC;   // 0 or 64 within the selected matrix

        // stage W chunk: rows kbase..kbase+63, 128 cols
        {
            const int col = tx << 2;
            #pragma unroll
            for (int it = 0; it < 8; ++it) {
                int kl = (it << 3) + ty;
                *(float4*)(sW + kl * DD + col) =
                    *(const float4*)(W + (kbase + kl) * DD + col);
            }
        }
        // stage A chunk transposed: sAT[k][r] = A[n0+r][kbase+k]
        {
            const int kg = (t & 15) << 2;
            const int rr = t >> 4;
            #pragma unroll
            for (int it = 0; it < 4; ++it) {
                int r = rr + (it << 4);
                int n = n0 + r;
                float4 v = make_float4(0.f, 0.f, 0.f, 0.f);
                if (n < N) v = *(const float4*)(A + (size_t)n * DD + kbase + kg);
                sAT[(kg + 0) * APAD + r] = v.x;
                sAT[(kg + 1) * APAD + r] = v.y;
                sAT[(kg + 2) * APAD + r] = v.z;
                sAT[(kg + 3) * APAD + r] = v.w;
            }
        }
        __syncthreads();

        #pragma unroll 4
        for (int k = 0; k < KC; ++k) {
            float4 w4 = *(const float4*)(sW  + k * DD   + (tx << 2));
            float4 aA = *(const float4*)(sAT + k * APAD + (ty << 3));
            float4 aB = *(const float4*)(sAT + k * APAD + (ty << 3) + 4);
            float a[8] = {aA.x, aA.y, aA.z, aA.w, aB.x, aB.y, aB.z, aB.w};
            float w[4] = {w4.x, w4.y, w4.z, w4.w};
            #pragma unroll
            for (int i = 0; i < 8; ++i)
                #pragma unroll
                for (int j = 0; j < 4; ++j)
                    acc[i][j] = fmaf(a[i], w[j], acc[i][j]);
        }
        __syncthreads();
    }

    // epilogue: +bias, LayerNorm (row reduce over 32 lanes), PReLU, store
    const float alpha = alpha_p[0];
    const int c0 = tx << 2;
    const float4 gv = *(const float4*)(lng  + c0);
    const float4 bv = *(const float4*)(lnb  + c0);
    const float4 iv = *(const float4*)(bias + c0);
    const float gA[4]  = {gv.x, gv.y, gv.z, gv.w};
    const float bA[4]  = {bv.x, bv.y, bv.z, bv.w};
    const float biA[4] = {iv.x, iv.y, iv.z, iv.w};

    #pragma unroll
    for (int i = 0; i < 8; ++i) {
        float x[4];
        float s = 0.f, s2 = 0.f;
        #pragma unroll
        for (int j = 0; j < 4; ++j) {
            x[j] = acc[i][j] + biA[j];
            s  += x[j];
            s2 += x[j] * x[j];
        }
        #pragma unroll
        for (int off = 16; off > 0; off >>= 1) {
            s  += __shfl_xor(s,  off, 32);
            s2 += __shfl_xor(s2, off, 32);
        }
        const float mean = s * (1.f / 128.f);
        float var = s2 * (1.f / 128.f) - mean * mean;
        var = var < 0.f ? 0.f : var;
        const float rstd = rsqrtf(var + 1e-5f);
        float o[4];
        #pragma unroll
        for (int j = 0; j < 4; ++j) {
            float y = (x[j] - mean) * rstd * gA[j] + bA[j];
            o[j] = (y >= 0.f) ? y : alpha * y;
        }
        const int n = n0 + (ty << 3) + i;
        if (n < N)
            *(float4*)(hout + (size_t)n * DD + c0) =
                make_float4(o[0], o[1], o[2], o[3]);
    }
}

// ---------------------------------------------------------------------------
// Classifier: logits = LN(relu(h @ W1 + b1)) @ W2 + b2   (H=128, C=2)
// Same GEMM structure (K=128, 2 chunks), full fusion including the D->2
// projection via a second 32-lane shuffle reduction.
// ---------------------------------------------------------------------------
__global__ __launch_bounds__(256) void k_cls(
    const float* __restrict__ hin, const float* __restrict__ W1,
    const float* __restrict__ b1, const float* __restrict__ lng,
    const float* __restrict__ lnb, const float* __restrict__ W2,
    const float* __restrict__ b2, float* __restrict__ out, int N)
{
    __shared__ float sW[KC * DD];
    __shared__ float sAT[KC * APAD];

    const int t  = threadIdx.x;
    const int tx = t & 31;
    const int ty = t >> 5;
    const int n0 = blockIdx.x * BM;

    float acc[8][4];
    #pragma unroll
    for (int i = 0; i < 8; ++i)
        #pragma unroll
        for (int j = 0; j < 4; ++j) acc[i][j] = 0.f;

    #pragma unroll
    for (int ch = 0; ch < 2; ++ch) {
        const int kbase = ch * KC;
        {
            const int col = tx << 2;
            #pragma unroll
            for (int it = 0; it < 8; ++it) {
                int kl = (it << 3) + ty;
                *(float4*)(sW + kl * DD + col) =
                    *(const float4*)(W1 + (kbase + kl) * DD + col);
            }
        }
        {
            const int kg = (t & 15) << 2;
            const int rr = t >> 4;
            #pragma unroll
            for (int it = 0; it < 4; ++it) {
                int r = rr + (it << 4);
                int n = n0 + r;
                float4 v = make_float4(0.f, 0.f, 0.f, 0.f);
                if (n < N) v = *(const float4*)(hin + (size_t)n * DD + kbase + kg);
                sAT[(kg + 0) * APAD + r] = v.x;
                sAT[(kg + 1) * APAD + r] = v.y;
                sAT[(kg + 2) * APAD + r] = v.z;
                sAT[(kg + 3) * APAD + r] = v.w;
            }
        }
        __syncthreads();

        #pragma unroll 4
        for (int k = 0; k < KC; ++k) {
            float4 w4 = *(const float4*)(sW  + k * DD   + (tx << 2));
            float4 aA = *(const float4*)(sAT + k * APAD + (ty << 3));
            float4 aB = *(const float4*)(sAT + k * APAD + (ty << 3) + 4);
            float a[8] = {aA.x, aA.y, aA.z, aA.w, aB.x, aB.y, aB.z, aB.w};
            float w[4] = {w4.x, w4.y, w4.z, w4.w};
            #pragma unroll
            for (int i = 0; i < 8; ++i)
                #pragma unroll
                for (int j = 0; j < 4; ++j)
                    acc[i][j] = fmaf(a[i], w[j], acc[i][j]);
        }
        __syncthreads();
    }

    const int c0 = tx << 2;
    const float4 gv  = *(const float4*)(lng + c0);
    const float4 bv  = *(const float4*)(lnb + c0);
    const float4 b1v = *(const float4*)(b1  + c0);
    // W2 is [128][2] row-major: float4 at 2*c0 covers (c0,0),(c0,1),(c0+1,0),(c0+1,1)
    const float4 w2a = *(const float4*)(W2 + (c0 << 1));
    const float4 w2b = *(const float4*)(W2 + (c0 << 1) + 4);
    const float gA[4]  = {gv.x, gv.y, gv.z, gv.w};
    const float bA[4]  = {bv.x, bv.y, bv.z, bv.w};
    const float b1A[4] = {b1v.x, b1v.y, b1v.z, b1v.w};
    const float w2c0[4] = {w2a.x, w2a.z, w2b.x, w2b.z};
    const float w2c1[4] = {w2a.y, w2a.w, w2b.y, w2b.w};
    const float b2v0 = b2[0], b2v1 = b2[1];

    #pragma unroll
    for (int i = 0; i < 8; ++i) {
        float x[4];
        float s = 0.f, s2 = 0.f;
        #pragma unroll
        for (int j = 0; j < 4; ++j) {
            float r = acc[i][j] + b1A[j];
            x[j] = r > 0.f ? r : 0.f;        // relu
            s  += x[j];
            s2 += x[j] * x[j];
        }
        #pragma unroll
        for (int off = 16; off > 0; off >>= 1) {
            s  += __shfl_xor(s,  off, 32);
            s2 += __shfl_xor(s2, off, 32);
        }
        const float mean = s * (1.f / 128.f);
        float var = s2 * (1.f / 128.f) - mean * mean;
        var = var < 0.f ? 0.f : var;
        const float rstd = rsqrtf(var + 1e-5f);
        float p0 = 0.f, p1 = 0.f;
        #pragma unroll
        for (int j = 0; j < 4; ++j) {
            float z = (x[j] - mean) * rstd * gA[j] + bA[j];
            p0 = fmaf(z, w2c0[j], p0);
            p1 = fmaf(z, w2c1[j], p1);
        }
        #pragma unroll
        for (int off = 16; off > 0; off >>= 1) {
            p0 += __shfl_xor(p0, off, 32);
            p1 += __shfl_xor(p1, off, 32);
        }
        const int n = n0 + (ty << 3) + i;
        if (tx == 0 && n < N) {
            out[n * 2 + 0] = p0 + b2v0;
            out[n * 2 + 1] = p1 + b2v1;
        }
    }
}

// ---------------------------------------------------------------------------
extern "C" void kernel_launch(void* const* d_in, const int* in_sizes, int n_in,
                              void* d_out, int out_size, void* d_ws, size_t ws_size,
                              hipStream_t stream) {
    const float* features = (const float*)d_in[0];
    const int*   eidx     = (const int*)  d_in[1];
    const float* ew       = (const float*)d_in[2];
    const float* Wrel     = (const float*)d_in[3];
    const float* Wroot    = (const float*)d_in[4];
    const float* bias     = (const float*)d_in[5];
    const float* lng      = (const float*)d_in[6];
    const float* lnb      = (const float*)d_in[7];
    const float* alpha    = (const float*)d_in[8];
    const float* W1       = (const float*)d_in[9];
    const float* b1       = (const float*)d_in[10];
    const float* clng     = (const float*)d_in[11];
    const float* clnb     = (const float*)d_in[12];
    const float* W2       = (const float*)d_in[13];
    const float* b2       = (const float*)d_in[14];

    const int N = in_sizes[0] / DD;
    const int E = in_sizes[2];
    const int L = in_sizes[8];

    // workspace: agg | h0 | h1  (N*128 fp32 each = 51.2 MB each)
    float* agg = (float*)d_ws;
    float* h0  = agg + (size_t)N * DD;
    float* h1  = h0  + (size_t)N * DD;

    const int* src = eidx;
    const int* dst = eidx + E;

    const int sc_blocks = (E * 32 + 255) / 256;
    const int gm_blocks = (N + BM - 1) / BM;

    const float* hin = features;
    for (int l = 0; l < L; ++l) {
        float* hout = (l & 1) ? h1 : h0;
        hipMemsetAsync(agg, 0, (size_t)N * DD * sizeof(float), stream);
        k_scatter<<<sc_blocks, 256, 0, stream>>>(hin, src, dst, ew, agg, E);
        k_layer<<<gm_blocks, 256, 0, stream>>>(
            agg, hin,
            Wrel + (size_t)l * DD * DD, Wroot + (size_t)l * DD * DD,
            bias + l * DD, lng + l * DD, lnb + l * DD, alpha + l,
            hout, N);
        hin = hout;
    }
    k_cls<<<gm_blocks, 256, 0, stream>>>(hin, W1, b1, clng, clnb, W2, b2,
                                         (float*)d_out, N);
}

// Round 2
// 1016.953 us; speedup vs baseline: 8.3689x; 8.3689x over previous
//
#include <hip/hip_runtime.h>
#include <math.h>

#define DD 128
#define BM 64
#define KC 64
#define APAD 68   // LDS stride for transposed A tile

// ===========================================================================
// Stage 1 (once per call): counting-sort edges by dst -> CSR
// ===========================================================================

__global__ __launch_bounds__(256) void k_hist(
    const int* __restrict__ dst, int* __restrict__ counts, int E)
{
    int e = blockIdx.x * 256 + threadIdx.x;
    if (e < E) atomicAdd(&counts[dst[e]], 1);
}

// per-block exclusive scan over 1024 elements (256 thr x 4)
__global__ __launch_bounds__(256) void k_scan1(
    const int* __restrict__ cnt, int* __restrict__ excl,
    int* __restrict__ bsum, int N)
{
    __shared__ int tmp[256];
    const int t = threadIdx.x;
    const int base = blockIdx.x * 1024 + t * 4;
    int v[4];
    #pragma unroll
    for (int i = 0; i < 4; ++i) v[i] = (base + i < N) ? cnt[base + i] : 0;
    const int s = v[0] + v[1] + v[2] + v[3];
    tmp[t] = s;
    __syncthreads();
    int val = s;
    for (int off = 1; off < 256; off <<= 1) {
        int u = (t >= off) ? tmp[t - off] : 0;
        __syncthreads();
        val += u;
        tmp[t] = val;
        __syncthreads();
    }
    int run = val - s;  // exclusive prefix of this thread
    #pragma unroll
    for (int i = 0; i < 4; ++i) {
        if (base + i < N) excl[base + i] = run;
        run += v[i];
    }
    if (t == 255) bsum[blockIdx.x] = val;  // block total
}

// single-block exclusive scan of block sums (nb <= 256)
__global__ __launch_bounds__(256) void k_scan2(int* __restrict__ bsum, int nb)
{
    __shared__ int tmp[256];
    const int t = threadIdx.x;
    const int s = (t < nb) ? bsum[t] : 0;
    tmp[t] = s;
    __syncthreads();
    int val = s;
    for (int off = 1; off < 256; off <<= 1) {
        int u = (t >= off) ? tmp[t - off] : 0;
        __syncthreads();
        val += u;
        tmp[t] = val;
        __syncthreads();
    }
    if (t < nb) bsum[t] = val - s;
}

__global__ __launch_bounds__(256) void k_scan3(
    const int* __restrict__ excl, const int* __restrict__ bsum,
    int* __restrict__ starts, int* __restrict__ cursor, int N, int E)
{
    int i = blockIdx.x * 256 + threadIdx.x;
    if (i < N) {
        int v = excl[i] + bsum[i >> 10];
        starts[i] = v;
        cursor[i] = v;
    }
    if (i == 0) starts[N] = E;
}

// scatter edge records into dst-sorted order; fold edge weight in now
__global__ __launch_bounds__(256) void k_permute(
    const int* __restrict__ src, const int* __restrict__ dst,
    const float* __restrict__ ew, int* __restrict__ cursor,
    int2* __restrict__ edges_s, int E)
{
    int e = blockIdx.x * 256 + threadIdx.x;
    if (e >= E) return;
    int d = dst[e];
    int pos = atomicAdd(&cursor[d], 1);
    edges_s[pos] = make_int2(src[e], __float_as_int(ew[e]));
}

// ===========================================================================
// Stage 2 (per layer): gather-based segment sum. One 64-lane wave per node,
// each lane owns 2 columns (float2). Coalesced 512 B row reads, mostly L3.
// Writes EVERY row (zero for isolated nodes) -> no memset needed.
// ===========================================================================
__global__ __launch_bounds__(256) void k_gather(
    const float* __restrict__ h, const int* __restrict__ starts,
    const int2* __restrict__ edges, float* __restrict__ agg, int N)
{
    const int w = (blockIdx.x * 256 + threadIdx.x) >> 6;
    if (w >= N) return;
    const int lane = (threadIdx.x & 63) << 1;
    const int s0 = starts[w];
    const int s1 = starts[w + 1];
    float2 a0 = make_float2(0.f, 0.f), a1 = make_float2(0.f, 0.f);
    int j = s0;
    for (; j + 2 <= s1; j += 2) {
        const int2 e0 = edges[j];
        const int2 e1 = edges[j + 1];
        const float w0 = __int_as_float(e0.y);
        const float w1 = __int_as_float(e1.y);
        const float2 v0 = *(const float2*)(h + (size_t)e0.x * DD + lane);
        const float2 v1 = *(const float2*)(h + (size_t)e1.x * DD + lane);
        a0.x = fmaf(v0.x, w0, a0.x); a0.y = fmaf(v0.y, w0, a0.y);
        a1.x = fmaf(v1.x, w1, a1.x); a1.y = fmaf(v1.y, w1, a1.y);
    }
    if (j < s1) {
        const int2 e0 = edges[j];
        const float w0 = __int_as_float(e0.y);
        const float2 v0 = *(const float2*)(h + (size_t)e0.x * DD + lane);
        a0.x = fmaf(v0.x, w0, a0.x); a0.y = fmaf(v0.y, w0, a0.y);
    }
    *(float2*)(agg + (size_t)w * DD + lane) =
        make_float2(a0.x + a1.x, a0.y + a1.y);
}

// ===========================================================================
// Fused: out = PReLU(LayerNorm(agg @ Wrel + h @ Wroot + bias))
// hout may alias agg: each block reads only its own 64 rows (into LDS)
// before the epilogue writes them back.
// ===========================================================================
__global__ __launch_bounds__(256) void k_layer(
    const float* __restrict__ agg, const float* __restrict__ hin,
    const float* __restrict__ Wrel, const float* __restrict__ Wroot,
    const float* __restrict__ bias, const float* __restrict__ lng,
    const float* __restrict__ lnb, const float* __restrict__ alpha_p,
    float* __restrict__ hout, int N)
{
    __shared__ float sW[KC * DD];
    __shared__ float sAT[KC * APAD];

    const int t  = threadIdx.x;
    const int tx = t & 31;
    const int ty = t >> 5;
    const int n0 = blockIdx.x * BM;

    float acc[8][4];
    #pragma unroll
    for (int i = 0; i < 8; ++i)
        #pragma unroll
        for (int j = 0; j < 4; ++j) acc[i][j] = 0.f;

    #pragma unroll
    for (int ch = 0; ch < 4; ++ch) {
        const float* A = (ch < 2) ? agg  : hin;
        const float* W = (ch < 2) ? Wrel : Wroot;
        const int kbase = (ch & 1) * KC;

        {
            const int col = tx << 2;
            #pragma unroll
            for (int it = 0; it < 8; ++it) {
                int kl = (it << 3) + ty;
                *(float4*)(sW + kl * DD + col) =
                    *(const float4*)(W + (kbase + kl) * DD + col);
            }
        }
        {
            const int kg = (t & 15) << 2;
            const int rr = t >> 4;
            #pragma unroll
            for (int it = 0; it < 4; ++it) {
                int r = rr + (it << 4);
                int n = n0 + r;
                float4 v = make_float4(0.f, 0.f, 0.f, 0.f);
                if (n < N) v = *(const float4*)(A + (size_t)n * DD + kbase + kg);
                sAT[(kg + 0) * APAD + r] = v.x;
                sAT[(kg + 1) * APAD + r] = v.y;
                sAT[(kg + 2) * APAD + r] = v.z;
                sAT[(kg + 3) * APAD + r] = v.w;
            }
        }
        __syncthreads();

        #pragma unroll 4
        for (int k = 0; k < KC; ++k) {
            float4 w4 = *(const float4*)(sW  + k * DD   + (tx << 2));
            float4 aA = *(const float4*)(sAT + k * APAD + (ty << 3));
            float4 aB = *(const float4*)(sAT + k * APAD + (ty << 3) + 4);
            float a[8] = {aA.x, aA.y, aA.z, aA.w, aB.x, aB.y, aB.z, aB.w};
            float w[4] = {w4.x, w4.y, w4.z, w4.w};
            #pragma unroll
            for (int i = 0; i < 8; ++i)
                #pragma unroll
                for (int j = 0; j < 4; ++j)
                    acc[i][j] = fmaf(a[i], w[j], acc[i][j]);
        }
        __syncthreads();
    }

    const float alpha = alpha_p[0];
    const int c0 = tx << 2;
    const float4 gv = *(const float4*)(lng  + c0);
    const float4 bv = *(const float4*)(lnb  + c0);
    const float4 iv = *(const float4*)(bias + c0);
    const float gA[4]  = {gv.x, gv.y, gv.z, gv.w};
    const float bA[4]  = {bv.x, bv.y, bv.z, bv.w};
    const float biA[4] = {iv.x, iv.y, iv.z, iv.w};

    #pragma unroll
    for (int i = 0; i < 8; ++i) {
        float x[4];
        float s = 0.f, s2 = 0.f;
        #pragma unroll
        for (int j = 0; j < 4; ++j) {
            x[j] = acc[i][j] + biA[j];
            s  += x[j];
            s2 += x[j] * x[j];
        }
        #pragma unroll
        for (int off = 16; off > 0; off >>= 1) {
            s  += __shfl_xor(s,  off, 32);
            s2 += __shfl_xor(s2, off, 32);
        }
        const float mean = s * (1.f / 128.f);
        float var = s2 * (1.f / 128.f) - mean * mean;
        var = var < 0.f ? 0.f : var;
        const float rstd = rsqrtf(var + 1e-5f);
        float o[4];
        #pragma unroll
        for (int j = 0; j < 4; ++j) {
            float y = (x[j] - mean) * rstd * gA[j] + bA[j];
            o[j] = (y >= 0.f) ? y : alpha * y;
        }
        const int n = n0 + (ty << 3) + i;
        if (n < N)
            *(float4*)(hout + (size_t)n * DD + c0) =
                make_float4(o[0], o[1], o[2], o[3]);
    }
}

// ===========================================================================
// Classifier: logits = LN(relu(h @ W1 + b1)) @ W2 + b2   (H=128, C=2)
// ===========================================================================
__global__ __launch_bounds__(256) void k_cls(
    const float* __restrict__ hin, const float* __restrict__ W1,
    const float* __restrict__ b1, const float* __restrict__ lng,
    const float* __restrict__ lnb, const float* __restrict__ W2,
    const float* __restrict__ b2, float* __restrict__ out, int N)
{
    __shared__ float sW[KC * DD];
    __shared__ float sAT[KC * APAD];

    const int t  = threadIdx.x;
    const int tx = t & 31;
    const int ty = t >> 5;
    const int n0 = blockIdx.x * BM;

    float acc[8][4];
    #pragma unroll
    for (int i = 0; i < 8; ++i)
        #pragma unroll
        for (int j = 0; j < 4; ++j) acc[i][j] = 0.f;

    #pragma unroll
    for (int ch = 0; ch < 2; ++ch) {
        const int kbase = ch * KC;
        {
            const int col = tx << 2;
            #pragma unroll
            for (int it = 0; it < 8; ++it) {
                int kl = (it << 3) + ty;
                *(float4*)(sW + kl * DD + col) =
                    *(const float4*)(W1 + (kbase + kl) * DD + col);
            }
        }
        {
            const int kg = (t & 15) << 2;
            const int rr = t >> 4;
            #pragma unroll
            for (int it = 0; it < 4; ++it) {
                int r = rr + (it << 4);
                int n = n0 + r;
                float4 v = make_float4(0.f, 0.f, 0.f, 0.f);
                if (n < N) v = *(const float4*)(hin + (size_t)n * DD + kbase + kg);
                sAT[(kg + 0) * APAD + r] = v.x;
                sAT[(kg + 1) * APAD + r] = v.y;
                sAT[(kg + 2) * APAD + r] = v.z;
                sAT[(kg + 3) * APAD + r] = v.w;
            }
        }
        __syncthreads();

        #pragma unroll 4
        for (int k = 0; k < KC; ++k) {
            float4 w4 = *(const float4*)(sW  + k * DD   + (tx << 2));
            float4 aA = *(const float4*)(sAT + k * APAD + (ty << 3));
            float4 aB = *(const float4*)(sAT + k * APAD + (ty << 3) + 4);
            float a[8] = {aA.x, aA.y, aA.z, aA.w, aB.x, aB.y, aB.z, aB.w};
            float w[4] = {w4.x, w4.y, w4.z, w4.w};
            #pragma unroll
            for (int i = 0; i < 8; ++i)
                #pragma unroll
                for (int j = 0; j < 4; ++j)
                    acc[i][j] = fmaf(a[i], w[j], acc[i][j]);
        }
        __syncthreads();
    }

    const int c0 = tx << 2;
    const float4 gv  = *(const float4*)(lng + c0);
    const float4 bv  = *(const float4*)(lnb + c0);
    const float4 b1v = *(const float4*)(b1  + c0);
    const float4 w2a = *(const float4*)(W2 + (c0 << 1));
    const float4 w2b = *(const float4*)(W2 + (c0 << 1) + 4);
    const float gA[4]  = {gv.x, gv.y, gv.z, gv.w};
    const float bA[4]  = {bv.x, bv.y, bv.z, bv.w};
    const float b1A[4] = {b1v.x, b1v.y, b1v.z, b1v.w};
    const float w2c0[4] = {w2a.x, w2a.z, w2b.x, w2b.z};
    const float w2c1[4] = {w2a.y, w2a.w, w2b.y, w2b.w};
    const float b2v0 = b2[0], b2v1 = b2[1];

    #pragma unroll
    for (int i = 0; i < 8; ++i) {
        float x[4];
        float s = 0.f, s2 = 0.f;
        #pragma unroll
        for (int j = 0; j < 4; ++j) {
            float r = acc[i][j] + b1A[j];
            x[j] = r > 0.f ? r : 0.f;
            s  += x[j];
            s2 += x[j] * x[j];
        }
        #pragma unroll
        for (int off = 16; off > 0; off >>= 1) {
            s  += __shfl_xor(s,  off, 32);
            s2 += __shfl_xor(s2, off, 32);
        }
        const float mean = s * (1.f / 128.f);
        float var = s2 * (1.f / 128.f) - mean * mean;
        var = var < 0.f ? 0.f : var;
        const float rstd = rsqrtf(var + 1e-5f);
        float p0 = 0.f, p1 = 0.f;
        #pragma unroll
        for (int j = 0; j < 4; ++j) {
            float z = (x[j] - mean) * rstd * gA[j] + bA[j];
            p0 = fmaf(z, w2c0[j], p0);
            p1 = fmaf(z, w2c1[j], p1);
        }
        #pragma unroll
        for (int off = 16; off > 0; off >>= 1) {
            p0 += __shfl_xor(p0, off, 32);
            p1 += __shfl_xor(p1, off, 32);
        }
        const int n = n0 + (ty << 3) + i;
        if (tx == 0 && n < N) {
            out[n * 2 + 0] = p0 + b2v0;
            out[n * 2 + 1] = p1 + b2v1;
        }
    }
}

// ===========================================================================
extern "C" void kernel_launch(void* const* d_in, const int* in_sizes, int n_in,
                              void* d_out, int out_size, void* d_ws, size_t ws_size,
                              hipStream_t stream) {
    const float* features = (const float*)d_in[0];
    const int*   eidx     = (const int*)  d_in[1];
    const float* ew       = (const float*)d_in[2];
    const float* Wrel     = (const float*)d_in[3];
    const float* Wroot    = (const float*)d_in[4];
    const float* bias     = (const float*)d_in[5];
    const float* lng      = (const float*)d_in[6];
    const float* lnb      = (const float*)d_in[7];
    const float* alpha    = (const float*)d_in[8];
    const float* W1       = (const float*)d_in[9];
    const float* b1       = (const float*)d_in[10];
    const float* clng     = (const float*)d_in[11];
    const float* clnb     = (const float*)d_in[12];
    const float* W2       = (const float*)d_in[13];
    const float* b2       = (const float*)d_in[14];

    const int N = in_sizes[0] / DD;
    const int E = in_sizes[2];
    const int L = in_sizes[8];

    // workspace layout
    float* bufA   = (float*)d_ws;                 // N*128 f
    float* bufB   = bufA + (size_t)N * DD;        // N*128 f
    int*   counts = (int*)(bufB + (size_t)N * DD);// N
    int*   excl   = counts + N;                   // N
    int*   starts = excl + N;                     // N+2 (pad for 8B align below)
    int*   cursor = starts + N + 2;               // N
    int*   bsum   = cursor + N;                   // 256
    int2*  edges_s= (int2*)(bsum + 256);          // E  (8B-aligned: 4N+258 ints)

    const int* src = eidx;
    const int* dst = eidx + E;

    const int eb = (E + 255) / 256;
    const int nb = (N + 1023) / 1024;
    const int gm_blocks = (N + BM - 1) / BM;
    const int ga_blocks = (N * 64 + 255) / 256;

    // ---- build CSR by dst (once per call) ----
    hipMemsetAsync(counts, 0, (size_t)N * sizeof(int), stream);
    k_hist  <<<eb, 256, 0, stream>>>(dst, counts, E);
    k_scan1 <<<nb, 256, 0, stream>>>(counts, excl, bsum, N);
    k_scan2 <<<1,  256, 0, stream>>>(bsum, nb);
    k_scan3 <<<(N + 255) / 256, 256, 0, stream>>>(excl, bsum, starts, cursor, N, E);
    k_permute<<<eb, 256, 0, stream>>>(src, dst, ew, cursor, edges_s, E);

    // ---- layers ----
    const float* hin = features;
    for (int l = 0; l < L; ++l) {
        float* agg = (l & 1) ? bufB : bufA;   // hout aliases agg (safe per-block)
        k_gather<<<ga_blocks, 256, 0, stream>>>(hin, starts, edges_s, agg, N);
        k_layer <<<gm_blocks, 256, 0, stream>>>(
            agg, hin,
            Wrel + (size_t)l * DD * DD, Wroot + (size_t)l * DD * DD,
            bias + l * DD, lng + l * DD, lnb + l * DD, alpha + l,
            agg, N);
        hin = agg;
    }
    k_cls<<<gm_blocks, 256, 0, stream>>>(hin, W1, b1, clng, clnb, W2, b2,
                                         (float*)d_out, N);
}

// Round 6
// 1012.408 us; speedup vs baseline: 8.4065x; 1.0045x over previous
//
#include <hip/hip_runtime.h>
#include <math.h>

#define DD 128
#define BM 64     // rows per block in fp32 GEMM kernels (proven R2 config)
#define KC 64
#define APAD 68   // LDS stride for transposed A tile

// ===========================================================================
// Stage 1 (once per call): counting-sort edges by dst -> CSR
// ===========================================================================
__global__ __launch_bounds__(256) void k_hist(
    const int* __restrict__ dst, int* __restrict__ counts, int E)
{
    int e = blockIdx.x * 256 + threadIdx.x;
    if (e < E) atomicAdd(&counts[dst[e]], 1);
}

// per-block exclusive scan over 1024 elements, IN-PLACE (excl may == cnt):
// every thread reads its 4 elements before the first barrier; writes after.
__global__ __launch_bounds__(256) void k_scan1(
    const int* cnt, int* excl, int* __restrict__ bsum, int N)
{
    __shared__ int tmp[256];
    const int t = threadIdx.x;
    const int base = blockIdx.x * 1024 + t * 4;
    int v[4];
    #pragma unroll
    for (int i = 0; i < 4; ++i) v[i] = (base + i < N) ? cnt[base + i] : 0;
    const int s = v[0] + v[1] + v[2] + v[3];
    tmp[t] = s;
    __syncthreads();
    int val = s;
    for (int off = 1; off < 256; off <<= 1) {
        int u = (t >= off) ? tmp[t - off] : 0;
        __syncthreads();
        val += u;
        tmp[t] = val;
        __syncthreads();
    }
    int run = val - s;
    #pragma unroll
    for (int i = 0; i < 4; ++i) {
        if (base + i < N) excl[base + i] = run;
        run += v[i];
    }
    if (t == 255) bsum[blockIdx.x] = val;
}

__global__ __launch_bounds__(256) void k_scan2(int* __restrict__ bsum, int nb)
{
    __shared__ int tmp[256];
    const int t = threadIdx.x;
    const int s = (t < nb) ? bsum[t] : 0;
    tmp[t] = s;
    __syncthreads();
    int val = s;
    for (int off = 1; off < 256; off <<= 1) {
        int u = (t >= off) ? tmp[t - off] : 0;
        __syncthreads();
        val += u;
        tmp[t] = val;
        __syncthreads();
    }
    if (t < nb) bsum[t] = val - s;
}

__global__ __launch_bounds__(256) void k_scan3(
    const int* __restrict__ excl, const int* __restrict__ bsum,
    int* __restrict__ starts, int N)
{
    int i = blockIdx.x * 256 + threadIdx.x;
    if (i < N) starts[i] = excl[i] + bsum[i >> 10];
}

// Destructive: advances starts[d]; afterwards starts[i] == orig starts[i+1],
// so gather reads segment [i ? starts[i-1] : 0, starts[i]).
__global__ __launch_bounds__(256) void k_permute(
    const int* __restrict__ src, const int* __restrict__ dst,
    const float* __restrict__ ew, int* __restrict__ starts,
    int2* __restrict__ edges_s, int E)
{
    int e = blockIdx.x * 256 + threadIdx.x;
    if (e >= E) return;
    int d = dst[e];
    int pos = atomicAdd(&starts[d], 1);
    edges_s[pos] = make_int2(src[e], __float_as_int(ew[e]));
}

// ===========================================================================
// Stage 2 (per layer): gather-based segment sum. One wave per node, each
// lane owns 2 columns. 4-deep edge unroll for memory-level parallelism.
// starts is the POST-PERMUTE (shifted) array: seg = [starts[w-1], starts[w]).
// ===========================================================================
__global__ __launch_bounds__(256) void k_gather(
    const float* __restrict__ h, const int* __restrict__ starts,
    const int2* __restrict__ edges, float* __restrict__ agg, int N)
{
    const int w = (blockIdx.x * 256 + threadIdx.x) >> 6;
    if (w >= N) return;
    const int lane = (threadIdx.x & 63) << 1;
    const int s0 = w ? starts[w - 1] : 0;
    const int s1 = starts[w];
    float2 a0 = make_float2(0.f, 0.f), a1 = make_float2(0.f, 0.f);
    int j = s0;
    for (; j + 4 <= s1; j += 4) {
        const int2 e0 = edges[j];
        const int2 e1 = edges[j + 1];
        const int2 e2 = edges[j + 2];
        const int2 e3 = edges[j + 3];
        const float2 v0 = *(const float2*)(h + (size_t)e0.x * DD + lane);
        const float2 v1 = *(const float2*)(h + (size_t)e1.x * DD + lane);
        const float2 v2 = *(const float2*)(h + (size_t)e2.x * DD + lane);
        const float2 v3 = *(const float2*)(h + (size_t)e3.x * DD + lane);
        const float w0 = __int_as_float(e0.y), w1 = __int_as_float(e1.y);
        const float w2 = __int_as_float(e2.y), w3 = __int_as_float(e3.y);
        a0.x = fmaf(v0.x, w0, a0.x); a0.y = fmaf(v0.y, w0, a0.y);
        a1.x = fmaf(v1.x, w1, a1.x); a1.y = fmaf(v1.y, w1, a1.y);
        a0.x = fmaf(v2.x, w2, a0.x); a0.y = fmaf(v2.y, w2, a0.y);
        a1.x = fmaf(v3.x, w3, a1.x); a1.y = fmaf(v3.y, w3, a1.y);
    }
    for (; j < s1; ++j) {
        const int2 e0 = edges[j];
        const float w0 = __int_as_float(e0.y);
        const float2 v0 = *(const float2*)(h + (size_t)e0.x * DD + lane);
        a0.x = fmaf(v0.x, w0, a0.x); a0.y = fmaf(v0.y, w0, a0.y);
    }
    *(float2*)(agg + (size_t)w * DD + lane) =
        make_float2(a0.x + a1.x, a0.y + a1.y);
}

// ===========================================================================
// Fused: out = PReLU(LayerNorm(agg @ Wrel + h @ Wroot + bias))
// PROVEN fp32 VALU GEMM (R2-passing, byte-identical). hout may alias agg.
// ===========================================================================
__global__ __launch_bounds__(256) void k_layer(
    const float* __restrict__ agg, const float* __restrict__ hin,
    const float* __restrict__ Wrel, const float* __restrict__ Wroot,
    const float* __restrict__ bias, const float* __restrict__ lng,
    const float* __restrict__ lnb, const float* __restrict__ alpha_p,
    float* __restrict__ hout, int N)
{
    __shared__ float sW[KC * DD];
    __shared__ float sAT[KC * APAD];

    const int t  = threadIdx.x;
    const int tx = t & 31;
    const int ty = t >> 5;
    const int n0 = blockIdx.x * BM;

    float acc[8][4];
    #pragma unroll
    for (int i = 0; i < 8; ++i)
        #pragma unroll
        for (int j = 0; j < 4; ++j) acc[i][j] = 0.f;

    #pragma unroll
    for (int ch = 0; ch < 4; ++ch) {
        const float* A = (ch < 2) ? agg  : hin;
        const float* W = (ch < 2) ? Wrel : Wroot;
        const int kbase = (ch & 1) * KC;

        {
            const int col = tx << 2;
            #pragma unroll
            for (int it = 0; it < 8; ++it) {
                int kl = (it << 3) + ty;
                *(float4*)(sW + kl * DD + col) =
                    *(const float4*)(W + (kbase + kl) * DD + col);
            }
        }
        {
            const int kg = (t & 15) << 2;
            const int rr = t >> 4;
            #pragma unroll
            for (int it = 0; it < 4; ++it) {
                int r = rr + (it << 4);
                int n = n0 + r;
                float4 v = make_float4(0.f, 0.f, 0.f, 0.f);
                if (n < N) v = *(const float4*)(A + (size_t)n * DD + kbase + kg);
                sAT[(kg + 0) * APAD + r] = v.x;
                sAT[(kg + 1) * APAD + r] = v.y;
                sAT[(kg + 2) * APAD + r] = v.z;
                sAT[(kg + 3) * APAD + r] = v.w;
            }
        }
        __syncthreads();

        #pragma unroll 4
        for (int k = 0; k < KC; ++k) {
            float4 w4 = *(const float4*)(sW  + k * DD   + (tx << 2));
            float4 aA = *(const float4*)(sAT + k * APAD + (ty << 3));
            float4 aB = *(const float4*)(sAT + k * APAD + (ty << 3) + 4);
            float a[8] = {aA.x, aA.y, aA.z, aA.w, aB.x, aB.y, aB.z, aB.w};
            float w[4] = {w4.x, w4.y, w4.z, w4.w};
            #pragma unroll
            for (int i = 0; i < 8; ++i)
                #pragma unroll
                for (int j = 0; j < 4; ++j)
                    acc[i][j] = fmaf(a[i], w[j], acc[i][j]);
        }
        __syncthreads();
    }

    const float alpha = alpha_p[0];
    const int c0 = tx << 2;
    const float4 gv = *(const float4*)(lng  + c0);
    const float4 bv = *(const float4*)(lnb  + c0);
    const float4 iv = *(const float4*)(bias + c0);
    const float gA[4]  = {gv.x, gv.y, gv.z, gv.w};
    const float bA[4]  = {bv.x, bv.y, bv.z, bv.w};
    const float biA[4] = {iv.x, iv.y, iv.z, iv.w};

    #pragma unroll
    for (int i = 0; i < 8; ++i) {
        float x[4];
        float s = 0.f, s2 = 0.f;
        #pragma unroll
        for (int j = 0; j < 4; ++j) {
            x[j] = acc[i][j] + biA[j];
            s  += x[j];
            s2 += x[j] * x[j];
        }
        #pragma unroll
        for (int off = 16; off > 0; off >>= 1) {
            s  += __shfl_xor(s,  off, 32);
            s2 += __shfl_xor(s2, off, 32);
        }
        const float mean = s * (1.f / 128.f);
        float var = s2 * (1.f / 128.f) - mean * mean;
        var = var < 0.f ? 0.f : var;
        const float rstd = rsqrtf(var + 1e-5f);
        float o[4];
        #pragma unroll
        for (int j = 0; j < 4; ++j) {
            float y = (x[j] - mean) * rstd * gA[j] + bA[j];
            o[j] = (y >= 0.f) ? y : alpha * y;
        }
        const int n = n0 + (ty << 3) + i;
        if (n < N)
            *(float4*)(hout + (size_t)n * DD + c0) =
                make_float4(o[0], o[1], o[2], o[3]);
    }
}

// ===========================================================================
// Classifier: logits = LN(relu(h @ W1 + b1)) @ W2 + b2  (PROVEN fp32, R2)
// ===========================================================================
__global__ __launch_bounds__(256) void k_cls(
    const float* __restrict__ hin, const float* __restrict__ W1,
    const float* __restrict__ b1, const float* __restrict__ lng,
    const float* __restrict__ lnb, const float* __restrict__ W2,
    const float* __restrict__ b2, float* __restrict__ out, int N)
{
    __shared__ float sW[KC * DD];
    __shared__ float sAT[KC * APAD];

    const int t  = threadIdx.x;
    const int tx = t & 31;
    const int ty = t >> 5;
    const int n0 = blockIdx.x * BM;

    float acc[8][4];
    #pragma unroll
    for (int i = 0; i < 8; ++i)
        #pragma unroll
        for (int j = 0; j < 4; ++j) acc[i][j] = 0.f;

    #pragma unroll
    for (int ch = 0; ch < 2; ++ch) {
        const int kbase = ch * KC;
        {
            const int col = tx << 2;
            #pragma unroll
            for (int it = 0; it < 8; ++it) {
                int kl = (it << 3) + ty;
                *(float4*)(sW + kl * DD + col) =
                    *(const float4*)(W1 + (kbase + kl) * DD + col);
            }
        }
        {
            const int kg = (t & 15) << 2;
            const int rr = t >> 4;
            #pragma unroll
            for (int it = 0; it < 4; ++it) {
                int r = rr + (it << 4);
                int n = n0 + r;
                float4 v = make_float4(0.f, 0.f, 0.f, 0.f);
                if (n < N) v = *(const float4*)(hin + (size_t)n * DD + kbase + kg);
                sAT[(kg + 0) * APAD + r] = v.x;
                sAT[(kg + 1) * APAD + r] = v.y;
                sAT[(kg + 2) * APAD + r] = v.z;
                sAT[(kg + 3) * APAD + r] = v.w;
            }
        }
        __syncthreads();

        #pragma unroll 4
        for (int k = 0; k < KC; ++k) {
            float4 w4 = *(const float4*)(sW  + k * DD   + (tx << 2));
            float4 aA = *(const float4*)(sAT + k * APAD + (ty << 3));
            float4 aB = *(const float4*)(sAT + k * APAD + (ty << 3) + 4);
            float a[8] = {aA.x, aA.y, aA.z, aA.w, aB.x, aB.y, aB.z, aB.w};
            float w[4] = {w4.x, w4.y, w4.z, w4.w};
            #pragma unroll
            for (int i = 0; i < 8; ++i)
                #pragma unroll
                for (int j = 0; j < 4; ++j)
                    acc[i][j] = fmaf(a[i], w[j], acc[i][j]);
        }
        __syncthreads();
    }

    const int c0 = tx << 2;
    const float4 gv  = *(const float4*)(lng + c0);
    const float4 bv  = *(const float4*)(lnb + c0);
    const float4 b1v = *(const float4*)(b1  + c0);
    const float4 w2a = *(const float4*)(W2 + (c0 << 1));
    const float4 w2b = *(const float4*)(W2 + (c0 << 1) + 4);
    const float gA[4]  = {gv.x, gv.y, gv.z, gv.w};
    const float bA[4]  = {bv.x, bv.y, bv.z, bv.w};
    const float b1A[4] = {b1v.x, b1v.y, b1v.z, b1v.w};
    const float w2c0[4] = {w2a.x, w2a.z, w2b.x, w2b.z};
    const float w2c1[4] = {w2a.y, w2a.w, w2b.y, w2b.w};
    const float b2v0 = b2[0], b2v1 = b2[1];

    #pragma unroll
    for (int i = 0; i < 8; ++i) {
        float x[4];
        float s = 0.f, s2 = 0.f;
        #pragma unroll
        for (int j = 0; j < 4; ++j) {
            float r = acc[i][j] + b1A[j];
            x[j] = r > 0.f ? r : 0.f;
            s  += x[j];
            s2 += x[j] * x[j];
        }
        #pragma unroll
        for (int off = 16; off > 0; off >>= 1) {
            s  += __shfl_xor(s,  off, 32);
            s2 += __shfl_xor(s2, off, 32);
        }
        const float mean = s * (1.f / 128.f);
        float var = s2 * (1.f / 128.f) - mean * mean;
        var = var < 0.f ? 0.f : var;
        const float rstd = rsqrtf(var + 1e-5f);
        float p0 = 0.f, p1 = 0.f;
        #pragma unroll
        for (int j = 0; j < 4; ++j) {
            float z = (x[j] - mean) * rstd * gA[j] + bA[j];
            p0 = fmaf(z, w2c0[j], p0);
            p1 = fmaf(z, w2c1[j], p1);
        }
        #pragma unroll
        for (int off = 16; off > 0; off >>= 1) {
            p0 += __shfl_xor(p0, off, 32);
            p1 += __shfl_xor(p1, off, 32);
        }
        const int n = n0 + (ty << 3) + i;
        if (tx == 0 && n < N) {
            out[n * 2 + 0] = p0 + b2v0;
            out[n * 2 + 1] = p1 + b2v1;
        }
    }
}

// ===========================================================================
extern "C" void kernel_launch(void* const* d_in, const int* in_sizes, int n_in,
                              void* d_out, int out_size, void* d_ws, size_t ws_size,
                              hipStream_t stream) {
    const float* features = (const float*)d_in[0];
    const int*   eidx     = (const int*)  d_in[1];
    const float* ew       = (const float*)d_in[2];
    const float* Wrel     = (const float*)d_in[3];
    const float* Wroot    = (const float*)d_in[4];
    const float* bias     = (const float*)d_in[5];
    const float* lng      = (const float*)d_in[6];
    const float* lnb      = (const float*)d_in[7];
    const float* alpha    = (const float*)d_in[8];
    const float* W1       = (const float*)d_in[9];
    const float* b1       = (const float*)d_in[10];
    const float* clng     = (const float*)d_in[11];
    const float* clnb     = (const float*)d_in[12];
    const float* W2       = (const float*)d_in[13];
    const float* b2       = (const float*)d_in[14];

    const int N = in_sizes[0] / DD;
    const int E = in_sizes[2];
    const int L = in_sizes[8];

    // workspace layout (all sections 16B-aligned; ~115.8 MB total)
    float* bufA   = (float*)d_ws;                  // N*128 f
    float* bufB   = bufA + (size_t)N * DD;         // N*128 f
    int2*  edges_s= (int2*)(bufB + (size_t)N * DD);// E
    int*   counts = (int*)(edges_s + E);           // N (scanned in-place)
    int*   starts = counts + N;                    // N (post-permute: shifted)
    int*   bsum   = starts + N;                    // 258

    const int* src = eidx;
    const int* dst = eidx + E;

    const int eb = (E + 255) / 256;
    const int nb = (N + 1023) / 1024;
    const int gm_blocks = (N + BM - 1) / BM;
    const int ga_blocks = (N * 64 + 255) / 256;

    // ---- build CSR by dst (once per call) ----
    hipMemsetAsync(counts, 0, (size_t)N * sizeof(int), stream);
    k_hist  <<<eb, 256, 0, stream>>>(dst, counts, E);
    k_scan1 <<<nb, 256, 0, stream>>>(counts, counts, bsum, N);   // in-place
    k_scan2 <<<1,  256, 0, stream>>>(bsum, nb);
    k_scan3 <<<(N + 255) / 256, 256, 0, stream>>>(counts, bsum, starts, N);
    k_permute<<<eb, 256, 0, stream>>>(src, dst, ew, starts, edges_s, E);

    // ---- layers ----
    const float* hin = features;
    for (int l = 0; l < L; ++l) {
        float* agg = (l & 1) ? bufB : bufA;   // hout aliases agg (per-block safe)
        k_gather<<<ga_blocks, 256, 0, stream>>>(hin, starts, edges_s, agg, N);
        k_layer <<<gm_blocks, 256, 0, stream>>>(
            agg, hin,
            Wrel + (size_t)l * DD * DD, Wroot + (size_t)l * DD * DD,
            bias + l * DD, lng + l * DD, lnb + l * DD, alpha + l,
            agg, N);
        hin = agg;
    }
    k_cls<<<gm_blocks, 256, 0, stream>>>(hin, W1, b1, clng, clnb, W2, b2,
                                         (float*)d_out, N);
}

// Round 7
// 972.410 us; speedup vs baseline: 8.7523x; 1.0411x over previous
//
#include <hip/hip_runtime.h>
#include <math.h>

#define DD 128
#define BM 128    // rows per block in k_layer
#define KCL 32    // K-chunk in k_layer
#define SP 129    // padded LDS stride (conflict-free: stride%32 == 1)
#define KC 64     // k_cls chunk (proven R2 config)
#define APAD 68
#define SPB 400   // nodes per permute bucket

// ===========================================================================
// Stage 1 (once per call): counting-sort edges by dst -> CSR
// ===========================================================================
__global__ __launch_bounds__(256) void k_hist(
    const int* __restrict__ dst, int* __restrict__ counts, int E)
{
    int e = blockIdx.x * 256 + threadIdx.x;
    if (e < E) atomicAdd(&counts[dst[e]], 1);
}

// per-block exclusive scan over 1024 elements, IN-PLACE (excl may == cnt)
__global__ __launch_bounds__(256) void k_scan1(
    const int* cnt, int* excl, int* __restrict__ bsum, int N)
{
    __shared__ int tmp[256];
    const int t = threadIdx.x;
    const int base = blockIdx.x * 1024 + t * 4;
    int v[4];
    #pragma unroll
    for (int i = 0; i < 4; ++i) v[i] = (base + i < N) ? cnt[base + i] : 0;
    const int s = v[0] + v[1] + v[2] + v[3];
    tmp[t] = s;
    __syncthreads();
    int val = s;
    for (int off = 1; off < 256; off <<= 1) {
        int u = (t >= off) ? tmp[t - off] : 0;
        __syncthreads();
        val += u;
        tmp[t] = val;
        __syncthreads();
    }
    int run = val - s;
    #pragma unroll
    for (int i = 0; i < 4; ++i) {
        if (base + i < N) excl[base + i] = run;
        run += v[i];
    }
    if (t == 255) bsum[blockIdx.x] = val;
}

__global__ __launch_bounds__(256) void k_scan2(int* __restrict__ bsum, int nb)
{
    __shared__ int tmp[256];
    const int t = threadIdx.x;
    const int s = (t < nb) ? bsum[t] : 0;
    tmp[t] = s;
    __syncthreads();
    int val = s;
    for (int off = 1; off < 256; off <<= 1) {
        int u = (t >= off) ? tmp[t - off] : 0;
        __syncthreads();
        val += u;
        tmp[t] = val;
        __syncthreads();
    }
    if (t < nb) bsum[t] = val - s;
}

// starts[i] = exclusive start of node i (PRISTINE, kept), sentinel starts[N]=E,
// and per-bucket cursor init for pass-1 of the permute.
__global__ __launch_bounds__(256) void k_scan3(
    const int* __restrict__ excl, const int* __restrict__ bsum,
    int* __restrict__ starts, int* __restrict__ cursor1, int N, int E)
{
    int i = blockIdx.x * 256 + threadIdx.x;
    if (i < N) {
        int v = excl[i] + bsum[i >> 10];
        starts[i] = v;
        if (i % SPB == 0) cursor1[i / SPB] = v;
        if (i == N - 1) starts[N] = E;
    }
}

// ---------------------------------------------------------------------------
// Permute pass 1: coarse-bucket edges (bucket = dst/SPB) with per-block LDS
// histogram; writes grouped per (block,bucket) -> mostly full-line writes.
// tmp record: (src, dst, ew_bits, 0)
// ---------------------------------------------------------------------------
__global__ __launch_bounds__(256) void k_bucket(
    const int* __restrict__ src, const int* __restrict__ dst,
    const float* __restrict__ ew, int* __restrict__ cursor1,
    int4* __restrict__ tmp, int E)
{
    __shared__ int hist[256];
    __shared__ int base[256];
    const int t = threadIdx.x;
    const int e0 = blockIdx.x * 2048;
    hist[t] = 0;
    __syncthreads();
    int myb[8], myr[8];
    #pragma unroll
    for (int u = 0; u < 8; ++u) {
        int e = e0 + u * 256 + t;
        if (e < E) {
            int b = dst[e] / SPB;
            myb[u] = b;
            myr[u] = atomicAdd(&hist[b], 1);
        } else myb[u] = -1;
    }
    __syncthreads();
    if (hist[t] > 0) base[t] = atomicAdd(&cursor1[t], hist[t]);
    __syncthreads();
    #pragma unroll
    for (int u = 0; u < 8; ++u) {
        int e = e0 + u * 256 + t;
        if (e < E)
            tmp[base[myb[u]] + myr[u]] =
                make_int4(src[e], dst[e], __float_as_int(ew[e]), 0);
    }
}

// ---------------------------------------------------------------------------
// Permute pass 2: one block per bucket; per-node cursors in LDS; final
// placement confined to the bucket's contiguous output window (L2-local).
// ---------------------------------------------------------------------------
__global__ __launch_bounds__(256) void k_place(
    const int4* __restrict__ tmp, const int* __restrict__ starts,
    int2* __restrict__ edges_s, int N, int E)
{
    __shared__ int cur[SPB];
    const int b  = blockIdx.x;
    const int n0 = b * SPB;
    const int n1 = min(N, n0 + SPB);
    const int t  = threadIdx.x;
    for (int i = t; i < n1 - n0; i += 256) cur[i] = starts[n0 + i];
    __syncthreads();
    const int r0 = starts[n0];
    const int r1 = (n1 < N) ? starts[n1] : E;
    for (int e = r0 + t; e < r1; e += 256) {
        int4 rec = tmp[e];
        int pos = atomicAdd(&cur[rec.y - n0], 1);
        edges_s[pos] = make_int2(rec.x, rec.z);
    }
}

// ===========================================================================
// Stage 2 (per layer): gather segment-sum. One wave per node; each 32-lane
// half handles one edge-row per load (float4/lane -> 2 rows per instruction),
// 8 edges in flight per iteration; cross-half combine via shfl_xor(32).
// ===========================================================================
__global__ __launch_bounds__(256) void k_gather(
    const float* __restrict__ h, const int* __restrict__ starts,
    const int2* __restrict__ edges, float* __restrict__ agg, int N)
{
    const int w = (blockIdx.x * 256 + threadIdx.x) >> 6;
    if (w >= N) return;
    const int lane = threadIdx.x & 63;
    const int half = lane >> 5;
    const int c4   = (lane & 31) << 2;
    const int s0 = starts[w];
    const int s1 = starts[w + 1];
    float4 a0 = make_float4(0.f, 0.f, 0.f, 0.f);
    float4 a1 = make_float4(0.f, 0.f, 0.f, 0.f);
    int j = s0;
    for (; j + 8 <= s1; j += 8) {
        const int2 eA = edges[j     + half];
        const int2 eB = edges[j + 2 + half];
        const int2 eC = edges[j + 4 + half];
        const int2 eD = edges[j + 6 + half];
        const float4 vA = *(const float4*)(h + (size_t)eA.x * DD + c4);
        const float4 vB = *(const float4*)(h + (size_t)eB.x * DD + c4);
        const float4 vC = *(const float4*)(h + (size_t)eC.x * DD + c4);
        const float4 vD = *(const float4*)(h + (size_t)eD.x * DD + c4);
        const float wA = __int_as_float(eA.y), wB = __int_as_float(eB.y);
        const float wC = __int_as_float(eC.y), wD = __int_as_float(eD.y);
        a0.x = fmaf(vA.x, wA, a0.x); a0.y = fmaf(vA.y, wA, a0.y);
        a0.z = fmaf(vA.z, wA, a0.z); a0.w = fmaf(vA.w, wA, a0.w);
        a1.x = fmaf(vB.x, wB, a1.x); a1.y = fmaf(vB.y, wB, a1.y);
        a1.z = fmaf(vB.z, wB, a1.z); a1.w = fmaf(vB.w, wB, a1.w);
        a0.x = fmaf(vC.x, wC, a0.x); a0.y = fmaf(vC.y, wC, a0.y);
        a0.z = fmaf(vC.z, wC, a0.z); a0.w = fmaf(vC.w, wC, a0.w);
        a1.x = fmaf(vD.x, wD, a1.x); a1.y = fmaf(vD.y, wD, a1.y);
        a1.z = fmaf(vD.z, wD, a1.z); a1.w = fmaf(vD.w, wD, a1.w);
    }
    for (; j < s1; j += 2) {
        const int idx = j + half;
        const bool ok = idx < s1;
        const int2 e = edges[ok ? idx : s1 - 1];
        const float wt = ok ? __int_as_float(e.y) : 0.f;
        const float4 v = *(const float4*)(h + (size_t)e.x * DD + c4);
        a0.x = fmaf(v.x, wt, a0.x); a0.y = fmaf(v.y, wt, a0.y);
        a0.z = fmaf(v.z, wt, a0.z); a0.w = fmaf(v.w, wt, a0.w);
    }
    float4 tot = make_float4(a0.x + a1.x, a0.y + a1.y, a0.z + a1.z, a0.w + a1.w);
    float4 oth;
    oth.x = __shfl_xor(tot.x, 32);
    oth.y = __shfl_xor(tot.y, 32);
    oth.z = __shfl_xor(tot.z, 32);
    oth.w = __shfl_xor(tot.w, 32);
    if (half == 0) {
        tot.x += oth.x; tot.y += oth.y; tot.z += oth.z; tot.w += oth.w;
        *(float4*)(agg + (size_t)w * DD + c4) = tot;
    }
}

// ===========================================================================
// Fused layer: out = PReLU(LN(agg @ Wrel + hin @ Wroot + bias))
// BM=128, KCL=32, 256 threads; thread tile 8x8 as split 4+4 rows/cols
// (rows ty*4..+3 and 64+ty*4..+3; cols tx*4..+3 and 64+tx*4..+3).
// LDS stride 129 -> conflict-free b128 reads. hout may alias agg
// (each block reads only its own rows before the epilogue stores).
// ===========================================================================
__global__ __launch_bounds__(256) void k_layer(
    const float* agg, const float* __restrict__ hin,
    const float* __restrict__ Wrel, const float* __restrict__ Wroot,
    const float* __restrict__ bias, const float* __restrict__ lng,
    const float* __restrict__ lnb, const float* __restrict__ alpha_p,
    float* hout, int N)
{
    __shared__ float sW[KCL * SP];    // sW[k][c]
    __shared__ float sAT[KCL * SP];   // sAT[k][r]

    const int t  = threadIdx.x;
    const int tx = t & 15;
    const int ty = t >> 4;
    const int n0 = blockIdx.x * BM;

    float acc[8][8];
    #pragma unroll
    for (int i = 0; i < 8; ++i)
        #pragma unroll
        for (int j = 0; j < 8; ++j) acc[i][j] = 0.f;

    for (int ch = 0; ch < 8; ++ch) {
        const float* A = (ch < 4) ? agg  : hin;
        const float* W = (ch < 4) ? Wrel : Wroot;
        const int kbase = (ch & 3) * KCL;
        if (ch) __syncthreads();
        {   // stage W chunk [KCL x 128]
            const int col = (t & 31) << 2;
            const int k0  = t >> 5;
            #pragma unroll
            for (int it = 0; it < 4; ++it) {
                int k = k0 + it * 8;
                *(float4*)(&sW[k * SP + col]) =
                    *(const float4*)(W + (size_t)(kbase + k) * DD + col);
            }
        }
        {   // stage A^T chunk: sAT[k][r] = A[n0+r][kbase+k]
            const int kg = (t & 7) << 2;
            const int rr = t >> 3;
            #pragma unroll
            for (int it = 0; it < 4; ++it) {
                int r = rr + it * 32;
                int n = n0 + r;
                float4 v = make_float4(0.f, 0.f, 0.f, 0.f);
                if (n < N) v = *(const float4*)(A + (size_t)n * DD + kbase + kg);
                sAT[(kg + 0) * SP + r] = v.x;
                sAT[(kg + 1) * SP + r] = v.y;
                sAT[(kg + 2) * SP + r] = v.z;
                sAT[(kg + 3) * SP + r] = v.w;
            }
        }
        __syncthreads();

        #pragma unroll 4
        for (int k = 0; k < KCL; ++k) {
            const float4 w0 = *(const float4*)(&sW[k * SP + (tx << 2)]);
            const float4 w1 = *(const float4*)(&sW[k * SP + 64 + (tx << 2)]);
            const float4 r0 = *(const float4*)(&sAT[k * SP + (ty << 2)]);
            const float4 r1 = *(const float4*)(&sAT[k * SP + 64 + (ty << 2)]);
            const float av[8] = {r0.x, r0.y, r0.z, r0.w, r1.x, r1.y, r1.z, r1.w};
            const float wv[8] = {w0.x, w0.y, w0.z, w0.w, w1.x, w1.y, w1.z, w1.w};
            #pragma unroll
            for (int i = 0; i < 8; ++i)
                #pragma unroll
                for (int j = 0; j < 8; ++j)
                    acc[i][j] = fmaf(av[i], wv[j], acc[i][j]);
        }
    }

    // epilogue: +bias, LN per row (reduce across the 16 tx lanes), PReLU
    const float alpha = alpha_p[0];
    const int c0 = tx << 2;
    const float4 bi0 = *(const float4*)(bias + c0);
    const float4 bi1 = *(const float4*)(bias + 64 + c0);
    const float4 g0  = *(const float4*)(lng + c0);
    const float4 g1  = *(const float4*)(lng + 64 + c0);
    const float4 be0 = *(const float4*)(lnb + c0);
    const float4 be1 = *(const float4*)(lnb + 64 + c0);
    const float biv[8] = {bi0.x, bi0.y, bi0.z, bi0.w, bi1.x, bi1.y, bi1.z, bi1.w};
    const float gv[8]  = {g0.x, g0.y, g0.z, g0.w, g1.x, g1.y, g1.z, g1.w};
    const float bev[8] = {be0.x, be0.y, be0.z, be0.w, be1.x, be1.y, be1.z, be1.w};

    #pragma unroll
    for (int i = 0; i < 8; ++i) {
        const int row = n0 + ((i < 4) ? (ty << 2) + i : 64 + (ty << 2) + (i - 4));
        float xv[8];
        float s = 0.f, s2 = 0.f;
        #pragma unroll
        for (int j = 0; j < 8; ++j) {
            const float x = acc[i][j] + biv[j];
            xv[j] = x; s += x; s2 = fmaf(x, x, s2);
        }
        #pragma unroll
        for (int off = 8; off > 0; off >>= 1) {
            s  += __shfl_xor(s,  off, 16);
            s2 += __shfl_xor(s2, off, 16);
        }
        const float mean = s * (1.f / 128.f);
        float var = s2 * (1.f / 128.f) - mean * mean;
        var = var < 0.f ? 0.f : var;
        const float rstd = rsqrtf(var + 1e-5f);
        if (row < N) {
            float o[8];
            #pragma unroll
            for (int j = 0; j < 8; ++j) {
                const float y = (xv[j] - mean) * rstd * gv[j] + bev[j];
                o[j] = (y >= 0.f) ? y : alpha * y;
            }
            *(float4*)(hout + (size_t)row * DD + c0) =
                make_float4(o[0], o[1], o[2], o[3]);
            *(float4*)(hout + (size_t)row * DD + 64 + c0) =
                make_float4(o[4], o[5], o[6], o[7]);
        }
    }
}

// ===========================================================================
// Classifier: logits = LN(relu(h @ W1 + b1)) @ W2 + b2  (PROVEN fp32, R2)
// ===========================================================================
__global__ __launch_bounds__(256) void k_cls(
    const float* __restrict__ hin, const float* __restrict__ W1,
    const float* __restrict__ b1, const float* __restrict__ lng,
    const float* __restrict__ lnb, const float* __restrict__ W2,
    const float* __restrict__ b2, float* __restrict__ out, int N)
{
    __shared__ float sW[KC * DD];
    __shared__ float sAT[KC * APAD];

    const int t  = threadIdx.x;
    const int tx = t & 31;
    const int ty = t >> 5;
    const int n0 = blockIdx.x * 64;

    float acc[8][4];
    #pragma unroll
    for (int i = 0; i < 8; ++i)
        #pragma unroll
        for (int j = 0; j < 4; ++j) acc[i][j] = 0.f;

    #pragma unroll
    for (int ch = 0; ch < 2; ++ch) {
        const int kbase = ch * KC;
        {
            const int col = tx << 2;
            #pragma unroll
            for (int it = 0; it < 8; ++it) {
                int kl = (it << 3) + ty;
                *(float4*)(sW + kl * DD + col) =
                    *(const float4*)(W1 + (kbase + kl) * DD + col);
            }
        }
        {
            const int kg = (t & 15) << 2;
            const int rr = t >> 4;
            #pragma unroll
            for (int it = 0; it < 4; ++it) {
                int r = rr + (it << 4);
                int n = n0 + r;
                float4 v = make_float4(0.f, 0.f, 0.f, 0.f);
                if (n < N) v = *(const float4*)(hin + (size_t)n * DD + kbase + kg);
                sAT[(kg + 0) * APAD + r] = v.x;
                sAT[(kg + 1) * APAD + r] = v.y;
                sAT[(kg + 2) * APAD + r] = v.z;
                sAT[(kg + 3) * APAD + r] = v.w;
            }
        }
        __syncthreads();

        #pragma unroll 4
        for (int k = 0; k < KC; ++k) {
            float4 w4 = *(const float4*)(sW  + k * DD   + (tx << 2));
            float4 aA = *(const float4*)(sAT + k * APAD + (ty << 3));
            float4 aB = *(const float4*)(sAT + k * APAD + (ty << 3) + 4);
            float a[8] = {aA.x, aA.y, aA.z, aA.w, aB.x, aB.y, aB.z, aB.w};
            float w[4] = {w4.x, w4.y, w4.z, w4.w};
            #pragma unroll
            for (int i = 0; i < 8; ++i)
                #pragma unroll
                for (int j = 0; j < 4; ++j)
                    acc[i][j] = fmaf(a[i], w[j], acc[i][j]);
        }
        __syncthreads();
    }

    const int c0 = tx << 2;
    const float4 gv  = *(const float4*)(lng + c0);
    const float4 bv  = *(const float4*)(lnb + c0);
    const float4 b1v = *(const float4*)(b1  + c0);
    const float4 w2a = *(const float4*)(W2 + (c0 << 1));
    const float4 w2b = *(const float4*)(W2 + (c0 << 1) + 4);
    const float gA[4]  = {gv.x, gv.y, gv.z, gv.w};
    const float bA[4]  = {bv.x, bv.y, bv.z, bv.w};
    const float b1A[4] = {b1v.x, b1v.y, b1v.z, b1v.w};
    const float w2c0[4] = {w2a.x, w2a.z, w2b.x, w2b.z};
    const float w2c1[4] = {w2a.y, w2a.w, w2b.y, w2b.w};
    const float b2v0 = b2[0], b2v1 = b2[1];

    #pragma unroll
    for (int i = 0; i < 8; ++i) {
        float x[4];
        float s = 0.f, s2 = 0.f;
        #pragma unroll
        for (int j = 0; j < 4; ++j) {
            float r = acc[i][j] + b1A[j];
            x[j] = r > 0.f ? r : 0.f;
            s  += x[j];
            s2 += x[j] * x[j];
        }
        #pragma unroll
        for (int off = 16; off > 0; off >>= 1) {
            s  += __shfl_xor(s,  off, 32);
            s2 += __shfl_xor(s2, off, 32);
        }
        const float mean = s * (1.f / 128.f);
        float var = s2 * (1.f / 128.f) - mean * mean;
        var = var < 0.f ? 0.f : var;
        const float rstd = rsqrtf(var + 1e-5f);
        float p0 = 0.f, p1 = 0.f;
        #pragma unroll
        for (int j = 0; j < 4; ++j) {
            float z = (x[j] - mean) * rstd * gA[j] + bA[j];
            p0 = fmaf(z, w2c0[j], p0);
            p1 = fmaf(z, w2c1[j], p1);
        }
        #pragma unroll
        for (int off = 16; off > 0; off >>= 1) {
            p0 += __shfl_xor(p0, off, 32);
            p1 += __shfl_xor(p1, off, 32);
        }
        const int n = n0 + (ty << 3) + i;
        if (tx == 0 && n < N) {
            out[n * 2 + 0] = p0 + b2v0;
            out[n * 2 + 1] = p1 + b2v1;
        }
    }
}

// ===========================================================================
extern "C" void kernel_launch(void* const* d_in, const int* in_sizes, int n_in,
                              void* d_out, int out_size, void* d_ws, size_t ws_size,
                              hipStream_t stream) {
    const float* features = (const float*)d_in[0];
    const int*   eidx     = (const int*)  d_in[1];
    const float* ew       = (const float*)d_in[2];
    const float* Wrel     = (const float*)d_in[3];
    const float* Wroot    = (const float*)d_in[4];
    const float* bias     = (const float*)d_in[5];
    const float* lng      = (const float*)d_in[6];
    const float* lnb      = (const float*)d_in[7];
    const float* alpha    = (const float*)d_in[8];
    const float* W1       = (const float*)d_in[9];
    const float* b1       = (const float*)d_in[10];
    const float* clng     = (const float*)d_in[11];
    const float* clnb     = (const float*)d_in[12];
    const float* W2       = (const float*)d_in[13];
    const float* b2       = (const float*)d_in[14];

    const int N = in_sizes[0] / DD;
    const int E = in_sizes[2];
    const int L = in_sizes[8];

    // workspace (~116.0 MB, within the proven >=116.8 MB budget)
    float* bufA    = (float*)d_ws;                   // N*128 f
    float* bufB    = bufA + (size_t)N * DD;          // N*128 f
    int2*  edges_s = (int2*)(bufB + (size_t)N * DD); // E
    int*   counts  = (int*)(edges_s + E);            // N (scanned in-place)
    int*   starts  = counts + N;                     // N+1 (pristine + sentinel)
    int*   bsum    = starts + N + 1;                 // 258
    int*   cursor1 = bsum + 258;                     // 256
    int4*  tmp     = (int4*)bufA;                    // E records, dead before layers

    const int* src = eidx;
    const int* dst = eidx + E;

    const int eb      = (E + 255) / 256;
    const int eb2k    = (E + 2047) / 2048;
    const int nb      = (N + 1023) / 1024;
    const int NBk     = (N + SPB - 1) / SPB;
    const int gm_blocks  = (N + BM - 1) / BM;
    const int cls_blocks = (N + 63) / 64;
    const int ga_blocks  = (N * 64 + 255) / 256;

    // ---- build CSR by dst (once per call) ----
    hipMemsetAsync(counts, 0, (size_t)N * sizeof(int), stream);
    k_hist  <<<eb, 256, 0, stream>>>(dst, counts, E);
    k_scan1 <<<nb, 256, 0, stream>>>(counts, counts, bsum, N);   // in-place
    k_scan2 <<<1,  256, 0, stream>>>(bsum, nb);
    k_scan3 <<<(N + 255) / 256, 256, 0, stream>>>(counts, bsum, starts, cursor1, N, E);
    k_bucket<<<eb2k, 256, 0, stream>>>(src, dst, ew, cursor1, tmp, E);
    k_place <<<NBk, 256, 0, stream>>>(tmp, starts, edges_s, N, E);

    // ---- layers ----
    const float* hin = features;
    for (int l = 0; l < L; ++l) {
        float* agg = (l & 1) ? bufB : bufA;   // hout aliases agg (per-block safe)
        k_gather<<<ga_blocks, 256, 0, stream>>>(hin, starts, edges_s, agg, N);
        k_layer <<<gm_blocks, 256, 0, stream>>>(
            agg, hin,
            Wrel + (size_t)l * DD * DD, Wroot + (size_t)l * DD * DD,
            bias + l * DD, lng + l * DD, lnb + l * DD, alpha + l,
            agg, N);
        hin = agg;
    }
    k_cls<<<cls_blocks, 256, 0, stream>>>(hin, W1, b1, clng, clnb, W2, b2,
                                          (float*)d_out, N);
}

// Round 8
// 961.160 us; speedup vs baseline: 8.8547x; 1.0117x over previous
//
#include <hip/hip_runtime.h>
#include <math.h>

#define DD 128
#define BM 64     // rows per block in k_layer (occupancy: 1563 blocks)
#define KCL 32    // K-chunk in k_layer
#define SP 129    // sW padded stride
#define SA 65     // sAT padded stride (64 rows + 1)
#define SPB 400   // nodes per permute bucket
#define CBM 128   // rows per block in MFMA k_cls

using fragT = __attribute__((ext_vector_type(8))) short;   // 8 bf16
using f32x4 = __attribute__((ext_vector_type(4))) float;

__device__ inline float trunc_bf16(float a) {
    return __uint_as_float(__float_as_uint(a) & 0xFFFF0000u);
}
__device__ inline short bf16bits(float a) {
    return (short)(__float_as_uint(a) >> 16);
}
// Exact 3-way bf16 split: x = f1 + f2 + f3 (3 x 8 significand bits = fp32)
__device__ inline void split8_3(const float4 v0, const float4 v1,
                                fragT& f1, fragT& f2, fragT& f3) {
    const float x[8] = {v0.x, v0.y, v0.z, v0.w, v1.x, v1.y, v1.z, v1.w};
    #pragma unroll
    for (int j = 0; j < 8; ++j) {
        const float a  = x[j];
        const float t1 = trunc_bf16(a);
        const float r1 = a - t1;
        const float t2 = trunc_bf16(r1);
        const float r2 = r1 - t2;
        f1[j] = bf16bits(a);
        f2[j] = bf16bits(t2);
        f3[j] = bf16bits(r2);
    }
}

// ===========================================================================
// Pack cls W1 (128x128) into MFMA-frag order, exact 3-way split.
// Per 64-K chunk c: [comp(3)][s(2)][t(8)][lane(64)][j(8)] shorts (24576/chunk)
//   k = c*64 + s*32 + (lane>>4)*8 + j ;  n = t*16 + (lane&15)
// ===========================================================================
__global__ __launch_bounds__(64) void k_pack_cls(
    const float* __restrict__ W1, short* __restrict__ packC)
{
    const int b = blockIdx.x;              // 32 blocks
    const int c = b >> 4, s = (b >> 3) & 1, t = b & 7;
    const int l = threadIdx.x;
    const int kg = c * 64 + s * 32 + ((l >> 4) << 3);
    const int n  = t * 16 + (l & 15);
    fragT c1, c2, c3;
    #pragma unroll
    for (int j = 0; j < 8; ++j) {
        const float a  = W1[(kg + j) * DD + n];
        const float t1 = trunc_bf16(a);
        const float r1 = a - t1;
        const float t2 = trunc_bf16(r1);
        const float r2 = r1 - t2;
        c1[j] = bf16bits(a);
        c2[j] = bf16bits(t2);
        c3[j] = bf16bits(r2);
    }
    short* base = packC + (size_t)c * 24576 + s * 4096 + t * 512 + l * 8;
    *(fragT*)(base)         = c1;
    *(fragT*)(base + 8192)  = c2;
    *(fragT*)(base + 16384) = c3;
}

// ===========================================================================
// Stage 1 (once per call): counting-sort edges by dst -> CSR
// ===========================================================================
__global__ __launch_bounds__(256) void k_hist(
    const int* __restrict__ dst, int* __restrict__ counts, int E)
{
    int e = blockIdx.x * 256 + threadIdx.x;
    if (e < E) atomicAdd(&counts[dst[e]], 1);
}

__global__ __launch_bounds__(256) void k_scan1(
    const int* cnt, int* excl, int* __restrict__ bsum, int N)
{
    __shared__ int tmp[256];
    const int t = threadIdx.x;
    const int base = blockIdx.x * 1024 + t * 4;
    int v[4];
    #pragma unroll
    for (int i = 0; i < 4; ++i) v[i] = (base + i < N) ? cnt[base + i] : 0;
    const int s = v[0] + v[1] + v[2] + v[3];
    tmp[t] = s;
    __syncthreads();
    int val = s;
    for (int off = 1; off < 256; off <<= 1) {
        int u = (t >= off) ? tmp[t - off] : 0;
        __syncthreads();
        val += u;
        tmp[t] = val;
        __syncthreads();
    }
    int run = val - s;
    #pragma unroll
    for (int i = 0; i < 4; ++i) {
        if (base + i < N) excl[base + i] = run;
        run += v[i];
    }
    if (t == 255) bsum[blockIdx.x] = val;
}

__global__ __launch_bounds__(256) void k_scan2(int* __restrict__ bsum, int nb)
{
    __shared__ int tmp[256];
    const int t = threadIdx.x;
    const int s = (t < nb) ? bsum[t] : 0;
    tmp[t] = s;
    __syncthreads();
    int val = s;
    for (int off = 1; off < 256; off <<= 1) {
        int u = (t >= off) ? tmp[t - off] : 0;
        __syncthreads();
        val += u;
        tmp[t] = val;
        __syncthreads();
    }
    if (t < nb) bsum[t] = val - s;
}

__global__ __launch_bounds__(256) void k_scan3(
    const int* __restrict__ excl, const int* __restrict__ bsum,
    int* __restrict__ starts, int* __restrict__ cursor1, int N, int E)
{
    int i = blockIdx.x * 256 + threadIdx.x;
    if (i < N) {
        int v = excl[i] + bsum[i >> 10];
        starts[i] = v;
        if (i % SPB == 0) cursor1[i / SPB] = v;
        if (i == N - 1) starts[N] = E;
    }
}

// Permute pass 1: coarse-bucket (dst/SPB) with LDS histogram; grouped writes.
__global__ __launch_bounds__(256) void k_bucket(
    const int* __restrict__ src, const int* __restrict__ dst,
    const float* __restrict__ ew, int* __restrict__ cursor1,
    int4* __restrict__ tmp, int E)
{
    __shared__ int hist[256];
    __shared__ int base[256];
    const int t = threadIdx.x;
    const int e0 = blockIdx.x * 2048;
    hist[t] = 0;
    __syncthreads();
    int myb[8], myr[8];
    #pragma unroll
    for (int u = 0; u < 8; ++u) {
        int e = e0 + u * 256 + t;
        if (e < E) {
            int b = dst[e] / SPB;
            myb[u] = b;
            myr[u] = atomicAdd(&hist[b], 1);
        } else myb[u] = -1;
    }
    __syncthreads();
    if (hist[t] > 0) base[t] = atomicAdd(&cursor1[t], hist[t]);
    __syncthreads();
    #pragma unroll
    for (int u = 0; u < 8; ++u) {
        int e = e0 + u * 256 + t;
        if (e < E)
            tmp[base[myb[u]] + myr[u]] =
                make_int4(src[e], dst[e], __float_as_int(ew[e]), 0);
    }
}

// Permute pass 2: one block per bucket; LDS cursors; L2-local placement.
__global__ __launch_bounds__(256) void k_place(
    const int4* __restrict__ tmp, const int* __restrict__ starts,
    int2* __restrict__ edges_s, int N, int E)
{
    __shared__ int cur[SPB];
    const int b  = blockIdx.x;
    const int n0 = b * SPB;
    const int n1 = min(N, n0 + SPB);
    const int t  = threadIdx.x;
    for (int i = t; i < n1 - n0; i += 256) cur[i] = starts[n0 + i];
    __syncthreads();
    const int r0 = starts[n0];
    const int r1 = (n1 < N) ? starts[n1] : E;
    for (int e = r0 + t; e < r1; e += 256) {
        int4 rec = tmp[e];
        int pos = atomicAdd(&cur[rec.y - n0], 1);
        edges_s[pos] = make_int2(rec.x, rec.z);
    }
}

// ===========================================================================
// Gather segment-sum: one wave/node, halves own alternating edges (float4).
// ===========================================================================
__global__ __launch_bounds__(256) void k_gather(
    const float* __restrict__ h, const int* __restrict__ starts,
    const int2* __restrict__ edges, float* __restrict__ agg, int N)
{
    const int w = (blockIdx.x * 256 + threadIdx.x) >> 6;
    if (w >= N) return;
    const int lane = threadIdx.x & 63;
    const int half = lane >> 5;
    const int c4   = (lane & 31) << 2;
    const int s0 = starts[w];
    const int s1 = starts[w + 1];
    float4 a0 = make_float4(0.f, 0.f, 0.f, 0.f);
    float4 a1 = make_float4(0.f, 0.f, 0.f, 0.f);
    int j = s0;
    for (; j + 8 <= s1; j += 8) {
        const int2 eA = edges[j     + half];
        const int2 eB = edges[j + 2 + half];
        const int2 eC = edges[j + 4 + half];
        const int2 eD = edges[j + 6 + half];
        const float4 vA = *(const float4*)(h + (size_t)eA.x * DD + c4);
        const float4 vB = *(const float4*)(h + (size_t)eB.x * DD + c4);
        const float4 vC = *(const float4*)(h + (size_t)eC.x * DD + c4);
        const float4 vD = *(const float4*)(h + (size_t)eD.x * DD + c4);
        const float wA = __int_as_float(eA.y), wB = __int_as_float(eB.y);
        const float wC = __int_as_float(eC.y), wD = __int_as_float(eD.y);
        a0.x = fmaf(vA.x, wA, a0.x); a0.y = fmaf(vA.y, wA, a0.y);
        a0.z = fmaf(vA.z, wA, a0.z); a0.w = fmaf(vA.w, wA, a0.w);
        a1.x = fmaf(vB.x, wB, a1.x); a1.y = fmaf(vB.y, wB, a1.y);
        a1.z = fmaf(vB.z, wB, a1.z); a1.w = fmaf(vB.w, wB, a1.w);
        a0.x = fmaf(vC.x, wC, a0.x); a0.y = fmaf(vC.y, wC, a0.y);
        a0.z = fmaf(vC.z, wC, a0.z); a0.w = fmaf(vC.w, wC, a0.w);
        a1.x = fmaf(vD.x, wD, a1.x); a1.y = fmaf(vD.y, wD, a1.y);
        a1.z = fmaf(vD.z, wD, a1.z); a1.w = fmaf(vD.w, wD, a1.w);
    }
    for (; j < s1; j += 2) {
        const int idx = j + half;
        const bool ok = idx < s1;
        const int2 e = edges[ok ? idx : s1 - 1];
        const float wt = ok ? __int_as_float(e.y) : 0.f;
        const float4 v = *(const float4*)(h + (size_t)e.x * DD + c4);
        a0.x = fmaf(v.x, wt, a0.x); a0.y = fmaf(v.y, wt, a0.y);
        a0.z = fmaf(v.z, wt, a0.z); a0.w = fmaf(v.w, wt, a0.w);
    }
    float4 tot = make_float4(a0.x + a1.x, a0.y + a1.y, a0.z + a1.z, a0.w + a1.w);
    float4 oth;
    oth.x = __shfl_xor(tot.x, 32);
    oth.y = __shfl_xor(tot.y, 32);
    oth.z = __shfl_xor(tot.z, 32);
    oth.w = __shfl_xor(tot.w, 32);
    if (half == 0) {
        tot.x += oth.x; tot.y += oth.y; tot.z += oth.z; tot.w += oth.w;
        *(float4*)(agg + (size_t)w * DD + c4) = tot;
    }
}

// ===========================================================================
// Fused layer: out = PReLU(LN(agg @ Wrel + hin @ Wroot + bias))
// BM=64, 128 threads (2 waves), 8x8 thread tile split 4+4 rows/cols.
// LDS ~24.8 KB -> 6 blocks/CU; grid 1563 -> full occupancy (~12 waves/CU).
// hout may alias agg (per-block: own-row reads precede stores).
// ===========================================================================
__global__ __launch_bounds__(128) void k_layer(
    const float* agg, const float* __restrict__ hin,
    const float* __restrict__ Wrel, const float* __restrict__ Wroot,
    const float* __restrict__ bias, const float* __restrict__ lng,
    const float* __restrict__ lnb, const float* __restrict__ alpha_p,
    float* hout, int N)
{
    __shared__ float sW[KCL * SP];    // sW[k][c], 16.5 KB
    __shared__ float sAT[KCL * SA];   // sAT[k][r], 8.3 KB

    const int t  = threadIdx.x;
    const int tx = t & 15;            // col groups: tx*4 and 64+tx*4
    const int ty = t >> 4;            // row groups: ty*4 and 32+ty*4 (0..7)
    const int n0 = blockIdx.x * BM;

    float acc[8][8];
    #pragma unroll
    for (int i = 0; i < 8; ++i)
        #pragma unroll
        for (int j = 0; j < 8; ++j) acc[i][j] = 0.f;

    for (int ch = 0; ch < 8; ++ch) {
        const float* A = (ch < 4) ? agg  : hin;
        const float* W = (ch < 4) ? Wrel : Wroot;
        const int kbase = (ch & 3) * KCL;
        if (ch) __syncthreads();
        {   // stage W chunk [KCL x 128], 8 passes of 128 float4
            const int col = (t & 31) << 2;
            const int k0  = t >> 5;   // 0..3
            #pragma unroll
            for (int it = 0; it < 8; ++it) {
                int k = k0 + it * 4;
                *(float4*)(&sW[k * SP + col]) =
                    *(const float4*)(W + (size_t)(kbase + k) * DD + col);
            }
        }
        {   // stage A^T chunk: sAT[k][r] = A[n0+r][kbase+k], 4 passes
            const int kg = (t & 7) << 2;
            const int rr = t >> 3;    // 0..15
            #pragma unroll
            for (int it = 0; it < 4; ++it) {
                int r = rr + it * 16;
                int n = n0 + r;
                float4 v = make_float4(0.f, 0.f, 0.f, 0.f);
                if (n < N) v = *(const float4*)(A + (size_t)n * DD + kbase + kg);
                sAT[(kg + 0) * SA + r] = v.x;
                sAT[(kg + 1) * SA + r] = v.y;
                sAT[(kg + 2) * SA + r] = v.z;
                sAT[(kg + 3) * SA + r] = v.w;
            }
        }
        __syncthreads();

        #pragma unroll 4
        for (int k = 0; k < KCL; ++k) {
            const float4 w0 = *(const float4*)(&sW[k * SP + (tx << 2)]);
            const float4 w1 = *(const float4*)(&sW[k * SP + 64 + (tx << 2)]);
            const float4 r0 = *(const float4*)(&sAT[k * SA + (ty << 2)]);
            const float4 r1 = *(const float4*)(&sAT[k * SA + 32 + (ty << 2)]);
            const float av[8] = {r0.x, r0.y, r0.z, r0.w, r1.x, r1.y, r1.z, r1.w};
            const float wv[8] = {w0.x, w0.y, w0.z, w0.w, w1.x, w1.y, w1.z, w1.w};
            #pragma unroll
            for (int i = 0; i < 8; ++i)
                #pragma unroll
                for (int j = 0; j < 8; ++j)
                    acc[i][j] = fmaf(av[i], wv[j], acc[i][j]);
        }
    }

    // epilogue: +bias, LN per row (reduce over 16 tx lanes), PReLU, store
    const float alpha = alpha_p[0];
    const int c0 = tx << 2;
    const float4 bi0 = *(const float4*)(bias + c0);
    const float4 bi1 = *(const float4*)(bias + 64 + c0);
    const float4 g0  = *(const float4*)(lng + c0);
    const float4 g1  = *(const float4*)(lng + 64 + c0);
    const float4 be0 = *(const float4*)(lnb + c0);
    const float4 be1 = *(const float4*)(lnb + 64 + c0);
    const float biv[8] = {bi0.x, bi0.y, bi0.z, bi0.w, bi1.x, bi1.y, bi1.z, bi1.w};
    const float gv[8]  = {g0.x, g0.y, g0.z, g0.w, g1.x, g1.y, g1.z, g1.w};
    const float bev[8] = {be0.x, be0.y, be0.z, be0.w, be1.x, be1.y, be1.z, be1.w};

    #pragma unroll
    for (int i = 0; i < 8; ++i) {
        const int row = n0 + ((i < 4) ? (ty << 2) + i : 32 + (ty << 2) + (i - 4));
        float xv[8];
        float s = 0.f, s2 = 0.f;
        #pragma unroll
        for (int j = 0; j < 8; ++j) {
            const float x = acc[i][j] + biv[j];
            xv[j] = x; s += x; s2 = fmaf(x, x, s2);
        }
        #pragma unroll
        for (int off = 8; off > 0; off >>= 1) {
            s  += __shfl_xor(s,  off, 16);
            s2 += __shfl_xor(s2, off, 16);
        }
        const float mean = s * (1.f / 128.f);
        float var = s2 * (1.f / 128.f) - mean * mean;
        var = var < 0.f ? 0.f : var;
        const float rstd = rsqrtf(var + 1e-5f);
        if (row < N) {
            float o[8];
            #pragma unroll
            for (int j = 0; j < 8; ++j) {
                const float y = (xv[j] - mean) * rstd * gv[j] + bev[j];
                o[j] = (y >= 0.f) ? y : alpha * y;
            }
            *(float4*)(hout + (size_t)row * DD + c0) =
                make_float4(o[0], o[1], o[2], o[3]);
            *(float4*)(hout + (size_t)row * DD + 64 + c0) =
                make_float4(o[4], o[5], o[6], o[7]);
        }
    }
}

// ===========================================================================
// Classifier (MFMA PROBE): logits = LN(relu(h @ W1 + b1)) @ W2 + b2
// Exact 3x3 bf16 decomposition, 6 MFMA terms. Block = 128 rows, 4 waves;
// wave owns 32 rows (2 m-tiles) x 128 cols (8 n-tiles); LN in 16-lane quads.
// absmax is the diagnostic: ~0.0039 => MFMA template clean.
// ===========================================================================
__global__ __launch_bounds__(256, 3) void k_cls(
    const float* __restrict__ hin, const short* __restrict__ packC,
    const float* __restrict__ b1, const float* __restrict__ lng,
    const float* __restrict__ lnb, const float* __restrict__ W2,
    const float* __restrict__ b2, float* __restrict__ out, int N)
{
    __shared__ short sB[24576];   // one 64-K chunk, 3 components, 48 KB

    const int t256 = threadIdx.x;
    const int lane = t256 & 63;
    const int w    = t256 >> 6;
    const int q    = lane >> 4;
    const int r16  = lane & 15;
    const int rowbase = blockIdx.x * CBM + w * 32;

    f32x4 acc[2][8];
    #pragma unroll
    for (int mt = 0; mt < 2; ++mt)
        #pragma unroll
        for (int t = 0; t < 8; ++t) acc[mt][t] = (f32x4)(0.f);

    for (int c = 0; c < 2; ++c) {
        if (c) __syncthreads();
        {   // copy 48 KB pre-packed chunk (3072 uint4)
            const uint4* srcp = (const uint4*)(packC + (size_t)c * 24576);
            uint4* dstp = (uint4*)sB;
            #pragma unroll
            for (int i = 0; i < 12; ++i)
                dstp[i * 256 + t256] = srcp[i * 256 + t256];
        }
        __syncthreads();

        const int kb = c * 64;
        #pragma unroll
        for (int s = 0; s < 2; ++s) {
            const int kq = kb + s * 32 + q * 8;
            fragT a1[2], a2[2], a3[2];
            #pragma unroll
            for (int mt = 0; mt < 2; ++mt) {
                const int row = rowbase + mt * 16 + r16;
                float4 v0 = make_float4(0.f, 0.f, 0.f, 0.f);
                float4 v1 = make_float4(0.f, 0.f, 0.f, 0.f);
                if (row < N) {
                    v0 = *(const float4*)(hin + (size_t)row * DD + kq);
                    v1 = *(const float4*)(hin + (size_t)row * DD + kq + 4);
                }
                split8_3(v0, v1, a1[mt], a2[mt], a3[mt]);
            }
            const short* sbase = sB + s * 4096 + lane * 8;
            #pragma unroll
            for (int t = 0; t < 8; ++t) {
                const fragT b1c = *(const fragT*)(sbase + t * 512);
                const fragT b2c = *(const fragT*)(sbase + 8192 + t * 512);
                const fragT b3c = *(const fragT*)(sbase + 16384 + t * 512);
                #pragma unroll
                for (int mt = 0; mt < 2; ++mt) {
                    acc[mt][t] = __builtin_amdgcn_mfma_f32_16x16x32_bf16(a1[mt], b1c, acc[mt][t], 0, 0, 0);
                    acc[mt][t] = __builtin_amdgcn_mfma_f32_16x16x32_bf16(a2[mt], b1c, acc[mt][t], 0, 0, 0);
                    acc[mt][t] = __builtin_amdgcn_mfma_f32_16x16x32_bf16(a1[mt], b2c, acc[mt][t], 0, 0, 0);
                    acc[mt][t] = __builtin_amdgcn_mfma_f32_16x16x32_bf16(a3[mt], b1c, acc[mt][t], 0, 0, 0);
                    acc[mt][t] = __builtin_amdgcn_mfma_f32_16x16x32_bf16(a2[mt], b2c, acc[mt][t], 0, 0, 0);
                    acc[mt][t] = __builtin_amdgcn_mfma_f32_16x16x32_bf16(a1[mt], b3c, acc[mt][t], 0, 0, 0);
                }
            }
        }
    }

    float b1v[8], gvv[8], bvv[8], w2c0[8], w2c1[8];
    #pragma unroll
    for (int t = 0; t < 8; ++t) {
        const int col = t * 16 + r16;
        b1v[t] = b1[col]; gvv[t] = lng[col]; bvv[t] = lnb[col];
        const float2 w2 = *(const float2*)(W2 + col * 2);
        w2c0[t] = w2.x; w2c1[t] = w2.y;
    }
    const float b2v0 = b2[0], b2v1 = b2[1];

    #pragma unroll
    for (int mt = 0; mt < 2; ++mt) {
        #pragma unroll
        for (int r = 0; r < 4; ++r) {
            const int row = rowbase + mt * 16 + q * 4 + r;
            float xv[8];
            float s = 0.f, s2 = 0.f;
            #pragma unroll
            for (int t = 0; t < 8; ++t) {
                float x = acc[mt][t][r] + b1v[t];
                x = x > 0.f ? x : 0.f;      // relu
                xv[t] = x; s += x; s2 = fmaf(x, x, s2);
            }
            #pragma unroll
            for (int off = 8; off > 0; off >>= 1) {
                s  += __shfl_xor(s,  off, 16);
                s2 += __shfl_xor(s2, off, 16);
            }
            const float mean = s * (1.f / 128.f);
            float var = s2 * (1.f / 128.f) - mean * mean;
            var = var < 0.f ? 0.f : var;
            const float rstd = rsqrtf(var + 1e-5f);
            float p0 = 0.f, p1 = 0.f;
            #pragma unroll
            for (int t = 0; t < 8; ++t) {
                const float z = (xv[t] - mean) * rstd * gvv[t] + bvv[t];
                p0 = fmaf(z, w2c0[t], p0);
                p1 = fmaf(z, w2c1[t], p1);
            }
            #pragma unroll
            for (int off = 8; off > 0; off >>= 1) {
                p0 += __shfl_xor(p0, off, 16);
                p1 += __shfl_xor(p1, off, 16);
            }
            if (r16 == 0 && row < N) {
                out[row * 2 + 0] = p0 + b2v0;
                out[row * 2 + 1] = p1 + b2v1;
            }
        }
    }
}

// ===========================================================================
extern "C" void kernel_launch(void* const* d_in, const int* in_sizes, int n_in,
                              void* d_out, int out_size, void* d_ws, size_t ws_size,
                              hipStream_t stream) {
    const float* features = (const float*)d_in[0];
    const int*   eidx     = (const int*)  d_in[1];
    const float* ew       = (const float*)d_in[2];
    const float* Wrel     = (const float*)d_in[3];
    const float* Wroot    = (const float*)d_in[4];
    const float* bias     = (const float*)d_in[5];
    const float* lng      = (const float*)d_in[6];
    const float* lnb      = (const float*)d_in[7];
    const float* alpha    = (const float*)d_in[8];
    const float* W1       = (const float*)d_in[9];
    const float* b1       = (const float*)d_in[10];
    const float* clng     = (const float*)d_in[11];
    const float* clnb     = (const float*)d_in[12];
    const float* W2       = (const float*)d_in[13];
    const float* b2       = (const float*)d_in[14];

    const int N = in_sizes[0] / DD;
    const int E = in_sizes[2];
    const int L = in_sizes[8];

    // workspace (R1 proved >=155 MB available; this uses ~116.2 MB)
    float* bufA    = (float*)d_ws;                   // N*128 f
    float* bufB    = bufA + (size_t)N * DD;          // N*128 f
    int2*  edges_s = (int2*)(bufB + (size_t)N * DD); // E
    int*   counts  = (int*)(edges_s + E);            // N (scanned in-place)
    int*   starts  = counts + N;                     // N+1 (pristine + sentinel)
    int*   bsum    = starts + N + 1;                 // 258
    int*   cursor1 = bsum + 258;                     // 256 (+2 pad -> 16B align)
    short* packC   = (short*)(cursor1 + 258);        // 49152 shorts (96 KB)
    int4*  tmp     = (int4*)bufA;                    // E recs, dead before layers

    const int* src = eidx;
    const int* dst = eidx + E;

    const int eb      = (E + 255) / 256;
    const int eb2k    = (E + 2047) / 2048;
    const int nb      = (N + 1023) / 1024;
    const int NBk     = (N + SPB - 1) / SPB;
    const int gm_blocks  = (N + BM - 1) / BM;
    const int cls_blocks = (N + CBM - 1) / CBM;
    const int ga_blocks  = (N * 64 + 255) / 256;

    // ---- pack cls W1 + build CSR by dst (once per call) ----
    k_pack_cls<<<32, 64, 0, stream>>>(W1, packC);
    hipMemsetAsync(counts, 0, (size_t)N * sizeof(int), stream);
    k_hist  <<<eb, 256, 0, stream>>>(dst, counts, E);
    k_scan1 <<<nb, 256, 0, stream>>>(counts, counts, bsum, N);   // in-place
    k_scan2 <<<1,  256, 0, stream>>>(bsum, nb);
    k_scan3 <<<(N + 255) / 256, 256, 0, stream>>>(counts, bsum, starts, cursor1, N, E);
    k_bucket<<<eb2k, 256, 0, stream>>>(src, dst, ew, cursor1, tmp, E);
    k_place <<<NBk, 256, 0, stream>>>(tmp, starts, edges_s, N, E);

    // ---- layers ----
    const float* hin = features;
    for (int l = 0; l < L; ++l) {
        float* agg = (l & 1) ? bufB : bufA;   // hout aliases agg (per-block safe)
        k_gather<<<ga_blocks, 256, 0, stream>>>(hin, starts, edges_s, agg, N);
        k_layer <<<gm_blocks, 128, 0, stream>>>(
            agg, hin,
            Wrel + (size_t)l * DD * DD, Wroot + (size_t)l * DD * DD,
            bias + l * DD, lng + l * DD, lnb + l * DD, alpha + l,
            agg, N);
        hin = agg;
    }
    k_cls<<<cls_blocks, 256, 0, stream>>>(hin, packC, b1, clng, clnb, W2, b2,
                                          (float*)d_out, N);
}